// Round 1
// baseline (332.874 us; speedup 1.0000x reference)
//
#include <hip/hip_runtime.h>
#include <math.h>

#define B_ 128
#define D_ 128
#define Q_ 256
#define L_ 1024

typedef __attribute__((ext_vector_type(8))) short s16x8;
typedef __attribute__((ext_vector_type(4))) float f32x4;
typedef unsigned short u16;

__device__ __forceinline__ u16 f2bf(float x) {
  unsigned u = __float_as_uint(x);
  u += 0x7FFF + ((u >> 16) & 1);  // round-to-nearest-even
  return (u16)(u >> 16);
}
__device__ __forceinline__ float bf2f(u16 h) {
  return __uint_as_float(((unsigned)h) << 16);
}
__device__ __forceinline__ uint2 pack4bf(float4 v) {
  uint2 r;
  r.x = ((unsigned)f2bf(v.y) << 16) | (unsigned)f2bf(v.x);
  r.y = ((unsigned)f2bf(v.w) << 16) | (unsigned)f2bf(v.z);
  return r;
}
__device__ __forceinline__ void split8(const float* x, s16x8& hi, s16x8& lo) {
#pragma unroll
  for (int j = 0; j < 8; j++) {
    u16 h = f2bf(x[j]);
    hi[j] = (short)h;
    lo[j] = (short)f2bf(x[j] - bf2f(h));
  }
}

// ---------------------------------------------------------------------------
// K0: split+transpose query once: query[b][d][q] fp32 -> qT hi/lo bf16 planes
// laid out [b][q][d] (d fast) so K1's A-fragments are single b128 loads.
// LDS transpose keeps both global read (along q) and global write (along d)
// fully coalesced. Same f2bf split as the old in-kernel split8 -> bit-exact.
// grid (Q/64, B), 256 thr.
// ---------------------------------------------------------------------------
__global__ __launch_bounds__(256) void k0_split(const float* __restrict__ query,
                                                u16* __restrict__ qhi,
                                                u16* __restrict__ qlo) {
  __shared__ float sm0[128][65];  // [d][q-in-tile], padded vs bank alias
  const int b = blockIdx.y, q0 = blockIdx.x * 64;
  const int tid = threadIdx.x;
  {
    const int dr = tid >> 4;        // 0..15
    const int lc = (tid & 15) * 4;  // 0..60
#pragma unroll
    for (int h = 0; h < 8; h++) {
      const int d = h * 16 + dr;
      float4 v = *(const float4*)(query + ((size_t)b * D_ + d) * Q_ + q0 + lc);
      sm0[d][lc] = v.x;
      sm0[d][lc + 1] = v.y;
      sm0[d][lc + 2] = v.z;
      sm0[d][lc + 3] = v.w;
    }
  }
  __syncthreads();
  const int qr = tid >> 2;        // 0..63
  const int dc = (tid & 3) * 32;  // 0,32,64,96
  u16* ph = qhi + ((size_t)b * Q_ + q0 + qr) * D_ + dc;
  u16* pl = qlo + ((size_t)b * Q_ + q0 + qr) * D_ + dc;
#pragma unroll
  for (int c = 0; c < 4; c++) {
    s16x8 hv, lv;
#pragma unroll
    for (int j = 0; j < 8; j++) {
      float x = sm0[dc + c * 8 + j][qr];
      u16 h = f2bf(x);
      hv[j] = (short)h;
      lv[j] = (short)f2bf(x - bf2f(h));
    }
    *(s16x8*)(ph + c * 8) = hv;
    *(s16x8*)(pl + c * 8) = lv;
  }
}

// ---------------------------------------------------------------------------
// K1: attn_q = softmax_q(ctx^T query), written (B,Q,L) fp32, plus partial
// second-softmax denominators pd[lt][b][q].
// New structure vs previous round:
//  - A-frags: single b128 loads from pre-split qT planes (no split8, no
//    strided scalar loads; 16x redundant query conversion eliminated).
//  - B-side: ctx tile (32d x 64l) converted ONCE per block per k-step into
//    transposed LDS CsT[l][d] hi/lo (8 elems/lane vs 32 before), fragments
//    read as b128. Chunk-XOR swizzle + 48-short rows keep conflicts ~2-way.
//  - launch_bounds(256,3): 12 waves/CU for latency hiding (was 8).
// Epilogue identical to previous round (bit-exact pipeline).
// grid (L/64=16, B), 256 thr = 4 waves (one 64q strip each).
// ---------------------------------------------------------------------------
__global__ __launch_bounds__(256, 3) void k1_attnq(
    const u16* __restrict__ qhi, const u16* __restrict__ qlo,
    const float* __restrict__ ctx, float* __restrict__ attq,
    float* __restrict__ pd) {
  __shared__ u16 CsH[64][48], CsL[64][48];  // [l][d-in-step], swizzled chunks
  __shared__ float sm[4][64], ss[4][64], fm[64], fs[64];
  const int lt = blockIdx.x, b = blockIdx.y;
  const int l0 = lt * 64;
  const int tid = threadIdx.x;
  const int wq = tid >> 6;  // wave = q-strip (0..3)
  const int lane = tid & 63, quad = lane >> 4, l15 = lane & 15;

  const float* Cb = ctx + (size_t)b * D_ * L_ + l0;
  const u16* Qh = qhi + ((size_t)b * Q_ + wq * 64 + l15) * D_;
  const u16* Ql = qlo + ((size_t)b * Q_ + wq * 64 + l15) * D_;

  // staging decomposition: thread -> (d-row, 8-l chunk)
  const int dd = tid >> 3;       // 0..31
  const int lc = (tid & 7) * 8;  // 0..56

  f32x4 acc[4][4];
#pragma unroll
  for (int mi = 0; mi < 4; mi++)
#pragma unroll
    for (int ni = 0; ni < 4; ni++) acc[mi][ni] = (f32x4){0.f, 0.f, 0.f, 0.f};

#pragma unroll 2
  for (int k0 = 0; k0 < D_; k0 += 32) {
    if (k0) __syncthreads();
    // ---- cooperative ctx convert: 32d x 64l fp32 -> CsT hi/lo (transposed)
    const float* cp = Cb + (size_t)(k0 + dd) * L_ + lc;
    float4 v0 = *(const float4*)cp;
    float4 v1 = *(const float4*)(cp + 4);
    float xv[8] = {v0.x, v0.y, v0.z, v0.w, v1.x, v1.y, v1.z, v1.w};
#pragma unroll
    for (int j = 0; j < 8; j++) {
      const int ll = lc + j;
      const int col = ((((dd >> 3) ^ (ll >> 3)) & 3) << 3) | (dd & 7);
      u16 h = f2bf(xv[j]);
      CsH[ll][col] = h;
      CsL[ll][col] = f2bf(xv[j] - bf2f(h));
    }
    __syncthreads();

    s16x8 bh[4], bl[4];
#pragma unroll
    for (int ni = 0; ni < 4; ni++) {
      const int ll = ni * 16 + l15;
      const int cc = ((quad ^ (ll >> 3)) & 3) << 3;
      bh[ni] = *(const s16x8*)&CsH[ll][cc];
      bl[ni] = *(const s16x8*)&CsL[ll][cc];
    }
#pragma unroll
    for (int mi = 0; mi < 4; mi++) {
      const s16x8 ah =
          *(const s16x8*)(Qh + (size_t)mi * 16 * D_ + k0 + quad * 8);
      const s16x8 al =
          *(const s16x8*)(Ql + (size_t)mi * 16 * D_ + k0 + quad * 8);
#pragma unroll
      for (int ni = 0; ni < 4; ni++) {
        acc[mi][ni] = __builtin_amdgcn_mfma_f32_16x16x32_bf16(
            ah, bh[ni], acc[mi][ni], 0, 0, 0);
        acc[mi][ni] = __builtin_amdgcn_mfma_f32_16x16x32_bf16(
            ah, bl[ni], acc[mi][ni], 0, 0, 0);
        acc[mi][ni] = __builtin_amdgcn_mfma_f32_16x16x32_bf16(
            al, bh[ni], acc[mi][ni], 0, 0, 0);
      }
    }
  }

  // ---- first softmax (over q), final in-block since block covers all 256 q
#pragma unroll
  for (int ni = 0; ni < 4; ni++) {
    float m = -1e30f;
#pragma unroll
    for (int mi = 0; mi < 4; mi++)
#pragma unroll
      for (int r = 0; r < 4; r++) m = fmaxf(m, acc[mi][ni][r]);
    m = fmaxf(m, __shfl_xor(m, 16));
    m = fmaxf(m, __shfl_xor(m, 32));
    float s = 0.f;
#pragma unroll
    for (int mi = 0; mi < 4; mi++)
#pragma unroll
      for (int r = 0; r < 4; r++) s += __expf(acc[mi][ni][r] - m);
    s += __shfl_xor(s, 16);
    s += __shfl_xor(s, 32);
    if (quad == 0) {
      sm[wq][ni * 16 + l15] = m;
      ss[wq][ni * 16 + l15] = s;
    }
  }
  __syncthreads();
  if (tid < 64) {
    float m0 = sm[0][tid], m1 = sm[1][tid], m2 = sm[2][tid], m3 = sm[3][tid];
    float M = fmaxf(fmaxf(m0, m1), fmaxf(m2, m3));
    float S = ss[0][tid] * __expf(m0 - M) + ss[1][tid] * __expf(m1 - M) +
              ss[2][tid] * __expf(m2 - M) + ss[3][tid] * __expf(m3 - M);
    fm[tid] = M;
    fs[tid] = 1.f / S;
  }
  __syncthreads();

  float fmv[4], fiv[4];
#pragma unroll
  for (int ni = 0; ni < 4; ni++) {
    fmv[ni] = fm[ni * 16 + l15];
    fiv[ni] = fs[ni * 16 + l15];
  }
  float* Ab = attq + ((size_t)b * Q_ + wq * 64) * L_ + l0;
  float dsum[4][4];
#pragma unroll
  for (int mi = 0; mi < 4; mi++)
#pragma unroll
    for (int r = 0; r < 4; r++) dsum[mi][r] = 0.f;
#pragma unroll
  for (int mi = 0; mi < 4; mi++)
#pragma unroll
    for (int r = 0; r < 4; r++) {
      const int q = mi * 16 + quad * 4 + r;
#pragma unroll
      for (int ni = 0; ni < 4; ni++) {
        float a = __expf(acc[mi][ni][r] - fmv[ni]) * fiv[ni];
        Ab[(size_t)q * L_ + ni * 16 + l15] = a;
        dsum[mi][r] += __expf(4.f * a);
      }
    }
#pragma unroll
  for (int mi = 0; mi < 4; mi++)
#pragma unroll
    for (int r = 0; r < 4; r++) {
      float v = dsum[mi][r];
      v += __shfl_xor(v, 1);
      v += __shfl_xor(v, 2);
      v += __shfl_xor(v, 4);
      v += __shfl_xor(v, 8);
      dsum[mi][r] = v;
    }
  if (l15 == 0) {
#pragma unroll
    for (int mi = 0; mi < 4; mi++)
#pragma unroll
      for (int r = 0; r < 4; r++)
        pd[(size_t)lt * (B_ * Q_) + b * Q_ + wq * 64 + mi * 16 + quad * 4 +
           r] = dsum[mi][r];
  }
}

// ---------------------------------------------------------------------------
// K1 legacy (previous round's kernel, verbatim): used only when the harness
// workspace is too small for the pre-split planes. No regression path.
// ---------------------------------------------------------------------------
__global__ __launch_bounds__(256, 2) void k1_attnq_legacy(
    const float* __restrict__ query, const float* __restrict__ ctx,
    float* __restrict__ attq, float* __restrict__ pd) {
  __shared__ float sm[4][64], ss[4][64], fm[64], fs[64];
  const int lt = blockIdx.x, b = blockIdx.y;
  const int l0 = lt * 64;
  const int tid = threadIdx.x;
  const int wq = tid >> 6;
  const int lane = tid & 63, quad = lane >> 4, l15 = lane & 15;

  const float* Qb = query + (size_t)b * D_ * Q_;
  const float* Cb = ctx + (size_t)b * D_ * L_ + l0;

  f32x4 acc[4][4];
#pragma unroll
  for (int mi = 0; mi < 4; mi++)
#pragma unroll
    for (int ni = 0; ni < 4; ni++) acc[mi][ni] = (f32x4){0.f, 0.f, 0.f, 0.f};

#pragma unroll 2
  for (int k0 = 0; k0 < D_; k0 += 32) {
    const int kq = k0 + quad * 8;
    s16x8 ah[4], al[4], bh[4], bl[4];
#pragma unroll
    for (int mi = 0; mi < 4; mi++) {
      const float* p = Qb + (size_t)kq * Q_ + wq * 64 + mi * 16 + l15;
      float x[8];
#pragma unroll
      for (int j = 0; j < 8; j++) x[j] = p[(size_t)j * Q_];
      split8(x, ah[mi], al[mi]);
    }
#pragma unroll
    for (int ni = 0; ni < 4; ni++) {
      const float* p = Cb + (size_t)kq * L_ + ni * 16 + l15;
      float x[8];
#pragma unroll
      for (int j = 0; j < 8; j++) x[j] = p[(size_t)j * L_];
      split8(x, bh[ni], bl[ni]);
    }
#pragma unroll
    for (int mi = 0; mi < 4; mi++)
#pragma unroll
      for (int ni = 0; ni < 4; ni++) {
        acc[mi][ni] = __builtin_amdgcn_mfma_f32_16x16x32_bf16(
            ah[mi], bh[ni], acc[mi][ni], 0, 0, 0);
        acc[mi][ni] = __builtin_amdgcn_mfma_f32_16x16x32_bf16(
            ah[mi], bl[ni], acc[mi][ni], 0, 0, 0);
        acc[mi][ni] = __builtin_amdgcn_mfma_f32_16x16x32_bf16(
            al[mi], bh[ni], acc[mi][ni], 0, 0, 0);
      }
  }

#pragma unroll
  for (int ni = 0; ni < 4; ni++) {
    float m = -1e30f;
#pragma unroll
    for (int mi = 0; mi < 4; mi++)
#pragma unroll
      for (int r = 0; r < 4; r++) m = fmaxf(m, acc[mi][ni][r]);
    m = fmaxf(m, __shfl_xor(m, 16));
    m = fmaxf(m, __shfl_xor(m, 32));
    float s = 0.f;
#pragma unroll
    for (int mi = 0; mi < 4; mi++)
#pragma unroll
      for (int r = 0; r < 4; r++) s += __expf(acc[mi][ni][r] - m);
    s += __shfl_xor(s, 16);
    s += __shfl_xor(s, 32);
    if (quad == 0) {
      sm[wq][ni * 16 + l15] = m;
      ss[wq][ni * 16 + l15] = s;
    }
  }
  __syncthreads();
  if (tid < 64) {
    float m0 = sm[0][tid], m1 = sm[1][tid], m2 = sm[2][tid], m3 = sm[3][tid];
    float M = fmaxf(fmaxf(m0, m1), fmaxf(m2, m3));
    float S = ss[0][tid] * __expf(m0 - M) + ss[1][tid] * __expf(m1 - M) +
              ss[2][tid] * __expf(m2 - M) + ss[3][tid] * __expf(m3 - M);
    fm[tid] = M;
    fs[tid] = 1.f / S;
  }
  __syncthreads();

  float fmv[4], fiv[4];
#pragma unroll
  for (int ni = 0; ni < 4; ni++) {
    fmv[ni] = fm[ni * 16 + l15];
    fiv[ni] = fs[ni * 16 + l15];
  }
  float* Ab = attq + ((size_t)b * Q_ + wq * 64) * L_ + l0;
  float dsum[4][4];
#pragma unroll
  for (int mi = 0; mi < 4; mi++)
#pragma unroll
    for (int r = 0; r < 4; r++) dsum[mi][r] = 0.f;
#pragma unroll
  for (int mi = 0; mi < 4; mi++)
#pragma unroll
    for (int r = 0; r < 4; r++) {
      const int q = mi * 16 + quad * 4 + r;
#pragma unroll
      for (int ni = 0; ni < 4; ni++) {
        float a = __expf(acc[mi][ni][r] - fmv[ni]) * fiv[ni];
        Ab[(size_t)q * L_ + ni * 16 + l15] = a;
        dsum[mi][r] += __expf(4.f * a);
      }
    }
#pragma unroll
  for (int mi = 0; mi < 4; mi++)
#pragma unroll
    for (int r = 0; r < 4; r++) {
      float v = dsum[mi][r];
      v += __shfl_xor(v, 1);
      v += __shfl_xor(v, 2);
      v += __shfl_xor(v, 4);
      v += __shfl_xor(v, 8);
      dsum[mi][r] = v;
    }
  if (l15 == 0) {
#pragma unroll
    for (int mi = 0; mi < 4; mi++)
#pragma unroll
      for (int r = 0; r < 4; r++)
        pd[(size_t)lt * (B_ * Q_) + b * Q_ + wq * 64 + mi * 16 + quad * 4 +
           r] = dsum[mi][r];
  }
}

// ---------------------------------------------------------------------------
// K2: invd[b][q] = 1 / sum over 16 l-tile partial denominators. 2 MB read.
// ---------------------------------------------------------------------------
__global__ __launch_bounds__(256) void k2_invd(const float* __restrict__ pd,
                                               float* __restrict__ invd) {
  const int i = blockIdx.x * 256 + threadIdx.x;  // 0..B*Q-1
  float s = 0.f;
#pragma unroll
  for (int t = 0; t < 16; t++) s += pd[(size_t)t * (B_ * Q_) + i];
  invd[i] = 1.f / s;
}

// ---------------------------------------------------------------------------
// K4: W[b][d][q] = sum_l ctx[b][d][l] * attn_c[b][q][l], bf16 MFMA,
// second softmax fused into B-staging; attention map written in place.
// (unchanged this round)
// ---------------------------------------------------------------------------
__global__ __launch_bounds__(256) void k4_weighted(
    const float* __restrict__ ctx, float* __restrict__ attn,
    const float* __restrict__ invd, float* __restrict__ W) {
  __shared__ unsigned short As[128][32];  // [d][l]
  __shared__ unsigned short Bs[64][32];   // [q][l]
  const int b = blockIdx.y, q0 = blockIdx.x * 64;
  const int tid = threadIdx.x;
  const int w = tid >> 6, lane = tid & 63, quad = lane >> 4, l15 = lane & 15;
  const int wd = (w >> 1) * 64, wn = (w & 1) * 32;

  const float* Cb = ctx + (size_t)b * D_ * L_;
  float* Ab = attn + ((size_t)b * Q_ + q0) * L_;

  const int lc = (tid & 7) * 4;  // 0..28
  const int rr = tid >> 3;       // 0..31
  const float id0 = invd[b * Q_ + q0 + rr];
  const float id1 = invd[b * Q_ + q0 + rr + 32];

  f32x4 acc[4][2];
#pragma unroll
  for (int mi = 0; mi < 4; mi++)
#pragma unroll
    for (int ni = 0; ni < 2; ni++) acc[mi][ni] = (f32x4){0.f, 0.f, 0.f, 0.f};

  for (int l0 = 0; l0 < L_; l0 += 32) {
    if (l0) __syncthreads();
#pragma unroll
    for (int h = 0; h < 4; h++) {  // A: 128d x 32l
      const int d = rr + h * 32;
      float4 cv = *(const float4*)(Cb + (size_t)d * L_ + l0 + lc);
      *(uint2*)&As[d][lc] = pack4bf(cv);
    }
#pragma unroll
    for (int h = 0; h < 2; h++) {  // B: 64q x 32l, fused second softmax
      const int q = rr + h * 32;
      float* p = Ab + (size_t)q * L_ + l0 + lc;
      float4 a = *(const float4*)p;
      const float idv = h ? id1 : id0;
      float4 t;
      t.x = __expf(4.f * a.x) * idv;
      t.y = __expf(4.f * a.y) * idv;
      t.z = __expf(4.f * a.z) * idv;
      t.w = __expf(4.f * a.w) * idv;
      *(float4*)p = t;  // attention map, in place
      *(uint2*)&Bs[q][lc] = pack4bf(t);
    }
    __syncthreads();

    s16x8 af[4], bq[2];
#pragma unroll
    for (int mi = 0; mi < 4; mi++)
      af[mi] = *(const s16x8*)&As[wd + mi * 16 + l15][quad * 8];
#pragma unroll
    for (int ni = 0; ni < 2; ni++)
      bq[ni] = *(const s16x8*)&Bs[wn + ni * 16 + l15][quad * 8];
#pragma unroll
    for (int mi = 0; mi < 4; mi++)
#pragma unroll
      for (int ni = 0; ni < 2; ni++)
        acc[mi][ni] = __builtin_amdgcn_mfma_f32_16x16x32_bf16(
            af[mi], bq[ni], acc[mi][ni], 0, 0, 0);
  }

  float* Wb = W + (size_t)b * D_ * Q_;
#pragma unroll
  for (int mi = 0; mi < 4; mi++)
#pragma unroll
    for (int ni = 0; ni < 2; ni++)
#pragma unroll
      for (int r = 0; r < 4; r++)
        Wb[(size_t)(wd + mi * 16 + quad * 4 + r) * Q_ + q0 + wn + ni * 16 +
           l15] = acc[mi][ni][r];
}

// ---------------------------------------------------------------------------
// d_out: [W (B*D*Q) | map (B*Q*L)]. K1 writes attn_q into the map region;
// K4 rewrites it in place as attn_c.
// Workspace layout (new path, ~19 MB): qT-hi | qT-lo | pd (16 strips) | invd.
// Fallbacks: ws >= 2.2MB -> legacy K1 with pd in ws; tiny ws -> legacy with
// pd in W-head (same as previous round).
// ---------------------------------------------------------------------------
extern "C" void kernel_launch(void* const* d_in, const int* in_sizes, int n_in,
                              void* d_out, int out_size, void* d_ws,
                              size_t ws_size, hipStream_t stream) {
  const float* query = (const float*)d_in[0];
  const float* ctx = (const float*)d_in[1];
  float* W = (float*)d_out;
  float* attn = (float*)d_out + (size_t)B_ * D_ * Q_;

  const size_t nQT = (size_t)B_ * Q_ * D_;  // elems per bf16 plane
  const size_t need_pd = (size_t)17 * B_ * Q_ * sizeof(float);
  const size_t need_full = nQT * 2 * sizeof(u16) + need_pd;

  if (d_ws && ws_size >= need_full) {
    u16* qh = (u16*)d_ws;
    u16* ql = qh + nQT;
    float* pd = (float*)(ql + nQT);
    float* invd = pd + (size_t)16 * B_ * Q_;
    k0_split<<<dim3(Q_ / 64, B_), 256, 0, stream>>>(query, qh, ql);
    k1_attnq<<<dim3(L_ / 64, B_), 256, 0, stream>>>(qh, ql, ctx, attn, pd);
    k2_invd<<<dim3(B_ * Q_ / 256), 256, 0, stream>>>(pd, invd);
    k4_weighted<<<dim3(Q_ / 64, B_), 256, 0, stream>>>(ctx, attn, invd, W);
  } else {
    float* pd = (d_ws && ws_size >= need_pd) ? (float*)d_ws : W;
    float* invd = pd + (size_t)16 * B_ * Q_;
    k1_attnq_legacy<<<dim3(L_ / 64, B_), 256, 0, stream>>>(query, ctx, attn,
                                                           pd);
    k2_invd<<<dim3(B_ * Q_ / 256), 256, 0, stream>>>(pd, invd);
    k4_weighted<<<dim3(Q_ / 64, B_), 256, 0, stream>>>(ctx, attn, invd, W);
  }
}